// Round 3
// baseline (148.453 us; speedup 1.0000x reference)
//
#include <hip/hip_runtime.h>
#include <math.h>

// RMSELoss(early=1, gap=0.5, late=2), train=True path:
//   d = t - x
//   v = d>=0.5 ? d^3 : (d<0 ? d^4 : 1)
//   out = sqrt(mean(v))

#define BLOCK 256
#define GRID  2048
#define NWAVE (BLOCK / 64)

__device__ __forceinline__ float vfun(float d) {
    float d2 = d * d;
    float e  = d2 * d;   // d^3
    float l  = d2 * d2;  // d^4
    return d >= 0.5f ? e : (d < 0.0f ? l : 1.0f);
}

__device__ __forceinline__ float vfun4(float4 a, float4 b) {
    return vfun(b.x - a.x) + vfun(b.y - a.y) + vfun(b.z - a.z) + vfun(b.w - a.w);
}

// __launch_bounds__(256, 4): 4 waves/EU min -> VGPR cap ~128, so the
// scheduler can afford to keep 16 float4 loads in flight (64 VGPRs of data).
// At VGPR=20 (round 2) it serialized the loads to chase occupancy we don't need.
__global__ __launch_bounds__(BLOCK, 4) void rmse_partial(
        const float4* __restrict__ x4,
        const float4* __restrict__ t4,
        const float*  __restrict__ x,
        const float*  __restrict__ t,
        float* __restrict__ block_sums,
        int n4, int n) {
    int idx    = blockIdx.x * blockDim.x + threadIdx.x;
    int stride = gridDim.x * blockDim.x;

    float acc0 = 0.0f, acc1 = 0.0f, acc2 = 0.0f, acc3 = 0.0f;
    int i = idx;

    // Unroll x8: 16 independent float4 loads (16 KiB/wave) in flight before
    // any consumption. At N=16Mi, n4=4Mi, stride=512K: exactly ONE iteration.
    for (; i + 7 * stride < n4; i += 8 * stride) {
        float4 a0 = x4[i];
        float4 a1 = x4[i + 1 * stride];
        float4 a2 = x4[i + 2 * stride];
        float4 a3 = x4[i + 3 * stride];
        float4 a4 = x4[i + 4 * stride];
        float4 a5 = x4[i + 5 * stride];
        float4 a6 = x4[i + 6 * stride];
        float4 a7 = x4[i + 7 * stride];
        float4 b0 = t4[i];
        float4 b1 = t4[i + 1 * stride];
        float4 b2 = t4[i + 2 * stride];
        float4 b3 = t4[i + 3 * stride];
        float4 b4 = t4[i + 4 * stride];
        float4 b5 = t4[i + 5 * stride];
        float4 b6 = t4[i + 6 * stride];
        float4 b7 = t4[i + 7 * stride];
        acc0 += vfun4(a0, b0);
        acc1 += vfun4(a1, b1);
        acc2 += vfun4(a2, b2);
        acc3 += vfun4(a3, b3);
        acc0 += vfun4(a4, b4);
        acc1 += vfun4(a5, b5);
        acc2 += vfun4(a6, b6);
        acc3 += vfun4(a7, b7);
    }
    // remainder (generality; empty at N=16Mi)
    for (; i < n4; i += stride) {
        acc0 += vfun4(x4[i], t4[i]);
    }
    // scalar tail (n % 4)
    if (idx == 0) {
        for (int j = n4 * 4; j < n; ++j) acc0 += vfun(t[j] - x[j]);
    }

    float acc = (acc0 + acc1) + (acc2 + acc3);

    // wave-64 reduction
    #pragma unroll
    for (int off = 32; off > 0; off >>= 1)
        acc += __shfl_down(acc, off, 64);

    __shared__ float smem[NWAVE];
    int lane = threadIdx.x & 63;
    int wave = threadIdx.x >> 6;
    if (lane == 0) smem[wave] = acc;
    __syncthreads();
    if (threadIdx.x == 0) {
        float s = 0.0f;
        #pragma unroll
        for (int w = 0; w < NWAVE; ++w) s += smem[w];
        block_sums[blockIdx.x] = s;   // every slot written — no memset needed
    }
}

__global__ __launch_bounds__(BLOCK) void rmse_final(
        const float* __restrict__ block_sums,
        float* __restrict__ out, float inv_n, int nb) {
    float s = 0.0f;
    for (int i = threadIdx.x; i < nb; i += BLOCK) s += block_sums[i];

    #pragma unroll
    for (int off = 32; off > 0; off >>= 1)
        s += __shfl_down(s, off, 64);

    __shared__ float smem[NWAVE];
    int lane = threadIdx.x & 63;
    int wave = threadIdx.x >> 6;
    if (lane == 0) smem[wave] = s;
    __syncthreads();
    if (threadIdx.x == 0) {
        float tot = 0.0f;
        #pragma unroll
        for (int w = 0; w < NWAVE; ++w) tot += smem[w];
        out[0] = sqrtf(tot * inv_n);
    }
}

extern "C" void kernel_launch(void* const* d_in, const int* in_sizes, int n_in,
                              void* d_out, int out_size, void* d_ws, size_t ws_size,
                              hipStream_t stream) {
    const float* x = (const float*)d_in[0];   // inputs
    const float* t = (const float*)d_in[1];   // targets
    float* out = (float*)d_out;
    float* ws  = (float*)d_ws;                // GRID floats of partial sums

    int n  = in_sizes[0];
    int n4 = n / 4;

    rmse_partial<<<GRID, BLOCK, 0, stream>>>(
        (const float4*)x, (const float4*)t, x, t, ws, n4, n);

    rmse_final<<<1, BLOCK, 0, stream>>>(ws, out, 1.0f / (float)n, GRID);
}

// Round 4
// 138.166 us; speedup vs baseline: 1.0745x; 1.0745x over previous
//
#include <hip/hip_runtime.h>
#include <math.h>

// RMSELoss(early=1, gap=0.5, late=2), train=True path:
//   d = t - x
//   v = d>=0.5 ? d^3 : (d<0 ? d^4 : 1)
//   out = sqrt(mean(v))
//
// R3 findings: kernel pinned at ~3.1 TB/s read regardless of ILP (2..16
// in-flight loads) and regardless of HBM vs L3 residency. This round:
// nontemporal loads (bypass L1/L2 allocation) to test whether cache
// allocation throttles streaming line throughput.

#define BLOCK 256
#define GRID  4096
#define NWAVE (BLOCK / 64)

typedef float vfloat4 __attribute__((ext_vector_type(4)));

__device__ __forceinline__ float vfun(float d) {
    float d2 = d * d;
    float e  = d2 * d;   // d^3
    float l  = d2 * d2;  // d^4
    return d >= 0.5f ? e : (d < 0.0f ? l : 1.0f);
}

__device__ __forceinline__ float vfun4(vfloat4 a, vfloat4 b) {
    return vfun(b.x - a.x) + vfun(b.y - a.y) + vfun(b.z - a.z) + vfun(b.w - a.w);
}

__global__ __launch_bounds__(BLOCK) void rmse_partial(
        const vfloat4* __restrict__ x4,
        const vfloat4* __restrict__ t4,
        const float*  __restrict__ x,
        const float*  __restrict__ t,
        float* __restrict__ block_sums,
        int n4, int n) {
    int idx    = blockIdx.x * blockDim.x + threadIdx.x;
    int stride = gridDim.x * blockDim.x;

    float acc0 = 0.0f, acc1 = 0.0f;
    int i = idx;

    // x4 unroll, nontemporal streaming loads. At N=16Mi, n4=4Mi,
    // stride=1Mi: exactly one unrolled iteration, no remainder.
    for (; i + 3 * stride < n4; i += 4 * stride) {
        vfloat4 a0 = __builtin_nontemporal_load(&x4[i]);
        vfloat4 a1 = __builtin_nontemporal_load(&x4[i + 1 * stride]);
        vfloat4 a2 = __builtin_nontemporal_load(&x4[i + 2 * stride]);
        vfloat4 a3 = __builtin_nontemporal_load(&x4[i + 3 * stride]);
        vfloat4 b0 = __builtin_nontemporal_load(&t4[i]);
        vfloat4 b1 = __builtin_nontemporal_load(&t4[i + 1 * stride]);
        vfloat4 b2 = __builtin_nontemporal_load(&t4[i + 2 * stride]);
        vfloat4 b3 = __builtin_nontemporal_load(&t4[i + 3 * stride]);
        acc0 += vfun4(a0, b0);
        acc1 += vfun4(a1, b1);
        acc0 += vfun4(a2, b2);
        acc1 += vfun4(a3, b3);
    }
    // remainder (generality; empty at N=16Mi)
    for (; i < n4; i += stride) {
        acc0 += vfun4(__builtin_nontemporal_load(&x4[i]),
                      __builtin_nontemporal_load(&t4[i]));
    }
    // scalar tail (n % 4)
    if (idx == 0) {
        for (int j = n4 * 4; j < n; ++j) acc0 += vfun(t[j] - x[j]);
    }

    float acc = acc0 + acc1;

    // wave-64 reduction
    #pragma unroll
    for (int off = 32; off > 0; off >>= 1)
        acc += __shfl_down(acc, off, 64);

    __shared__ float smem[NWAVE];
    int lane = threadIdx.x & 63;
    int wave = threadIdx.x >> 6;
    if (lane == 0) smem[wave] = acc;
    __syncthreads();
    if (threadIdx.x == 0) {
        float s = 0.0f;
        #pragma unroll
        for (int w = 0; w < NWAVE; ++w) s += smem[w];
        block_sums[blockIdx.x] = s;   // every slot written — no memset needed
    }
}

__global__ __launch_bounds__(1024) void rmse_final(
        const float* __restrict__ block_sums,
        float* __restrict__ out, float inv_n, int nb) {
    float s = 0.0f;
    for (int i = threadIdx.x; i < nb; i += 1024) s += block_sums[i];

    #pragma unroll
    for (int off = 32; off > 0; off >>= 1)
        s += __shfl_down(s, off, 64);

    __shared__ float smem[16];
    int lane = threadIdx.x & 63;
    int wave = threadIdx.x >> 6;
    if (lane == 0) smem[wave] = s;
    __syncthreads();
    if (threadIdx.x == 0) {
        float tot = 0.0f;
        #pragma unroll
        for (int w = 0; w < 16; ++w) tot += smem[w];
        out[0] = sqrtf(tot * inv_n);
    }
}

extern "C" void kernel_launch(void* const* d_in, const int* in_sizes, int n_in,
                              void* d_out, int out_size, void* d_ws, size_t ws_size,
                              hipStream_t stream) {
    const float* x = (const float*)d_in[0];   // inputs
    const float* t = (const float*)d_in[1];   // targets
    float* out = (float*)d_out;
    float* ws  = (float*)d_ws;                // GRID floats of partial sums

    int n  = in_sizes[0];
    int n4 = n / 4;

    rmse_partial<<<GRID, BLOCK, 0, stream>>>(
        (const vfloat4*)x, (const vfloat4*)t, x, t, ws, n4, n);

    rmse_final<<<1, 1024, 0, stream>>>(ws, out, 1.0f / (float)n, GRID);
}

// Round 5
// 137.399 us; speedup vs baseline: 1.0804x; 1.0056x over previous
//
#include <hip/hip_runtime.h>
#include <math.h>

// RMSELoss(early=1, gap=0.5, late=2), train=True path:
//   d = t - x ; v = d>=0.5 ? d^3 : (d<0 ? d^4 : 1) ; out = sqrt(mean(v))
//
// R4 findings: NT loads helped (~45.9 -> ~37 us inferred). Harness fill
// sustains 6.4 TB/s WRITE; our reads cap ~3.6 TB/s -> read-return-window
// bound. R5: block-chunked contiguous access (32 KB slab per block) for
// L3/channel locality of the in-flight window + block turnover, keep NT +
// 8 independent loads.

#define BLOCK  256
#define UNROLL 4
#define NWAVE  (BLOCK / 64)

typedef float vfloat4 __attribute__((ext_vector_type(4)));

__device__ __forceinline__ float vfun(float d) {
    float d2 = d * d;
    float e  = d2 * d;   // d^3
    float l  = d2 * d2;  // d^4
    return d >= 0.5f ? e : (d < 0.0f ? l : 1.0f);
}

__device__ __forceinline__ float vfun4(vfloat4 a, vfloat4 b) {
    return vfun(b.x - a.x) + vfun(b.y - a.y) + vfun(b.z - a.z) + vfun(b.w - a.w);
}

__global__ __launch_bounds__(BLOCK) void rmse_partial(
        const vfloat4* __restrict__ x4,
        const vfloat4* __restrict__ t4,
        const float*  __restrict__ x,
        const float*  __restrict__ t,
        float* __restrict__ block_sums,
        int n4, int n) {
    const int chunk = BLOCK * UNROLL;
    int base = blockIdx.x * chunk + threadIdx.x;

    float acc0 = 0.0f, acc1 = 0.0f;

    if (base + (UNROLL - 1) * BLOCK < n4 &&
        (int)((blockIdx.x + 1) * chunk) <= n4) {
        // Full chunk: 8 independent NT float4 loads, contiguous 16 KB per
        // array per block.
        vfloat4 a0 = __builtin_nontemporal_load(&x4[base]);
        vfloat4 a1 = __builtin_nontemporal_load(&x4[base + 1 * BLOCK]);
        vfloat4 a2 = __builtin_nontemporal_load(&x4[base + 2 * BLOCK]);
        vfloat4 a3 = __builtin_nontemporal_load(&x4[base + 3 * BLOCK]);
        vfloat4 b0 = __builtin_nontemporal_load(&t4[base]);
        vfloat4 b1 = __builtin_nontemporal_load(&t4[base + 1 * BLOCK]);
        vfloat4 b2 = __builtin_nontemporal_load(&t4[base + 2 * BLOCK]);
        vfloat4 b3 = __builtin_nontemporal_load(&t4[base + 3 * BLOCK]);
        acc0 += vfun4(a0, b0);
        acc1 += vfun4(a1, b1);
        acc0 += vfun4(a2, b2);
        acc1 += vfun4(a3, b3);
    } else {
        // Last partial chunk (generality; empty at N=16Mi)
        #pragma unroll
        for (int j = 0; j < UNROLL; ++j) {
            int i = base + j * BLOCK;
            if (i < n4)
                acc0 += vfun4(__builtin_nontemporal_load(&x4[i]),
                              __builtin_nontemporal_load(&t4[i]));
        }
    }
    // scalar tail (n % 4)
    if (blockIdx.x == 0 && threadIdx.x == 0) {
        for (int j = n4 * 4; j < n; ++j) acc0 += vfun(t[j] - x[j]);
    }

    float acc = acc0 + acc1;

    // wave-64 reduction
    #pragma unroll
    for (int off = 32; off > 0; off >>= 1)
        acc += __shfl_down(acc, off, 64);

    __shared__ float smem[NWAVE];
    int lane = threadIdx.x & 63;
    int wave = threadIdx.x >> 6;
    if (lane == 0) smem[wave] = acc;
    __syncthreads();
    if (threadIdx.x == 0) {
        float s = 0.0f;
        #pragma unroll
        for (int w = 0; w < NWAVE; ++w) s += smem[w];
        block_sums[blockIdx.x] = s;   // every slot written — no memset needed
    }
}

__global__ __launch_bounds__(1024) void rmse_final(
        const float* __restrict__ block_sums,
        float* __restrict__ out, float inv_n, int nb) {
    float s = 0.0f;
    for (int i = threadIdx.x; i < nb; i += 1024) s += block_sums[i];

    #pragma unroll
    for (int off = 32; off > 0; off >>= 1)
        s += __shfl_down(s, off, 64);

    __shared__ float smem[16];
    int lane = threadIdx.x & 63;
    int wave = threadIdx.x >> 6;
    if (lane == 0) smem[wave] = s;
    __syncthreads();
    if (threadIdx.x == 0) {
        float tot = 0.0f;
        #pragma unroll
        for (int w = 0; w < 16; ++w) tot += smem[w];
        out[0] = sqrtf(tot * inv_n);
    }
}

extern "C" void kernel_launch(void* const* d_in, const int* in_sizes, int n_in,
                              void* d_out, int out_size, void* d_ws, size_t ws_size,
                              hipStream_t stream) {
    const float* x = (const float*)d_in[0];   // inputs
    const float* t = (const float*)d_in[1];   // targets
    float* out = (float*)d_out;
    float* ws  = (float*)d_ws;                // grid floats of partial sums

    int n  = in_sizes[0];
    int n4 = n / 4;

    const int chunk = BLOCK * UNROLL;          // 1024 float4 per block
    int grid = (n4 + chunk - 1) / chunk;       // 4096 at N=16Mi

    rmse_partial<<<grid, BLOCK, 0, stream>>>(
        (const vfloat4*)x, (const vfloat4*)t, x, t, ws, n4, n);

    rmse_final<<<1, 1024, 0, stream>>>(ws, out, 1.0f / (float)n, grid);
}